// Round 10
// baseline (98.702 us; speedup 1.0000x reference)
//
#include <hip/hip_runtime.h>

// LaneNet discriminative loss, MI355X — 2-dispatch pipeline.
// preds: (4, 8, 280, 640) f32 ; targets: (4, 280, 640) i32 ; group_num = 5.
// out: [loss_dist, loss_var*0.01, loss_reg] f32.
//
// ws floats: PART [0, 700*45) ; VP [31500, 32200) ; CEN [32200, +4*48) ;
//            CNT (int) at [32392]  (zeroed by k_accum, which precedes k_var)
//
// k_accum: per-block partials (LDS-transpose reduce) + zero k_var's counter.
// k_var:   per-block batch-center recompute (ILP-deep, L2-hot) + var pass
//          + last-arriving-block finalize (threadfence/atomic release-acquire,
//          pattern validated on-HW in R5).

#define P_TOTAL (280 * 640)   // 179200 = 175 * 256 * 4
#define NBATCH 4
#define GN 5
#define CC 8
#define NVAL (GN * CC + GN)   // 45
#define LPAD 47               // odd stride => conflict-free LDS transpose
#define NBX 175
#define NUNIT (NBX * NBATCH)  // 700
#define WS_VP (NUNIT * NVAL)  // 31500
#define WS_CEN (WS_VP + NUNIT)
#define CEN_STRIDE 48
#define WS_CNT (WS_CEN + NBATCH * CEN_STRIDE)   // 32392, int slot

#define WAVE_RED(x)                          \
  do {                                       \
    x += __shfl_xor(x, 32, 64);              \
    x += __shfl_xor(x, 16, 64);              \
    x += __shfl_xor(x, 8, 64);               \
    x += __shfl_xor(x, 4, 64);               \
    x += __shfl_xor(x, 2, 64);               \
    x += __shfl_xor(x, 1, 64);               \
  } while (0)

__global__ __launch_bounds__(256) void k_accum(const float* __restrict__ preds,
                                               const int* __restrict__ targets,
                                               float* __restrict__ ws) {
  const int n = blockIdx.y;
  const int u = n * NBX + blockIdx.x;
  const int tid = threadIdx.x;
  const int p4 = (blockIdx.x * 256 + tid) * 4;   // exact: 175*256*4 = P_TOTAL

  // zero k_var's arrival counter (k_accum fully precedes k_var)
  if (u == 0 && tid == 0) ((int*)ws)[WS_CNT] = 0;

  const float* pn = preds + (size_t)n * CC * P_TOTAL;
  const int* tn = targets + (size_t)n * P_TOTAL;

  float acc[GN][CC];
  float cnt[GN];
#pragma unroll
  for (int g = 0; g < GN; ++g) {
    cnt[g] = 0.0f;
#pragma unroll
    for (int c = 0; c < CC; ++c) acc[g][c] = 0.0f;
  }

  {
    int4 t4 = *reinterpret_cast<const int4*>(tn + p4);
    int t[4] = {t4.x, t4.y, t4.z, t4.w};
    float4 v4[CC];
#pragma unroll
    for (int c = 0; c < CC; ++c)
      v4[c] = *reinterpret_cast<const float4*>(pn + (size_t)c * P_TOTAL + p4);
    float v[CC][4];
#pragma unroll
    for (int c = 0; c < CC; ++c) {
      v[c][0] = v4[c].x; v[c][1] = v4[c].y; v[c][2] = v4[c].z; v[c][3] = v4[c].w;
    }
#pragma unroll
    for (int s = 0; s < 4; ++s) {
#pragma unroll
      for (int g = 0; g < GN; ++g) {
        float m = (t[s] == g + 1) ? 1.0f : 0.0f;
        cnt[g] += m;
#pragma unroll
        for (int c = 0; c < CC; ++c) acc[g][c] = fmaf(m, v[c][s], acc[g][c]);
      }
    }
  }

  // block reduction via LDS transpose
  __shared__ float buf[256][LPAD];
  __shared__ float part4[NVAL][4];
#pragma unroll
  for (int g = 0; g < GN; ++g) {
#pragma unroll
    for (int c = 0; c < CC; ++c) buf[tid][g * CC + c] = acc[g][c];
    buf[tid][GN * CC + g] = cnt[g];
  }
  __syncthreads();

  if (tid < NVAL * 4) {
    const int k = tid >> 2;
    const int part = tid & 3;
    float s = 0.0f;
#pragma unroll
    for (int r = 0; r < 64; ++r) s += buf[(r << 2) + part][k];
    part4[k][part] = s;
  }
  __syncthreads();

  if (tid < NVAL)
    ws[u * NVAL + tid] =
        part4[tid][0] + part4[tid][1] + part4[tid][2] + part4[tid][3];
}

__global__ __launch_bounds__(256) void k_var(const float* __restrict__ preds,
                                             const int* __restrict__ targets,
                                             float* __restrict__ ws,
                                             float* __restrict__ out) {
  const int n = blockIdx.y;
  const int u = n * NBX + blockIdx.x;
  const int tid = threadIdx.x;
  const int lane = tid & 63;
  const int wv = tid >> 6;

  // ---- per-block center recompute from partials (L2-hot, ILP-deep) ----
  __shared__ float sums[NVAL][6];   // [k][part], padded
  __shared__ float tots[NVAL];
  __shared__ float center[GN][CC];
  if (tid < NVAL * 5) {
    const int k = tid % NVAL;
    const int part = tid / NVAL;    // 0..4 ; 35 independent loads each
    const float* base = ws + ((size_t)n * NBX + part * 35) * NVAL + k;
    float s = 0.0f;
#pragma unroll
    for (int i = 0; i < 35; ++i) s += base[i * NVAL];
    sums[k][part] = s;
  }
  __syncthreads();
  if (tid < NVAL)
    tots[tid] = sums[tid][0] + sums[tid][1] + sums[tid][2] + sums[tid][3] +
                sums[tid][4];
  __syncthreads();
  if (tid < GN * CC)
    center[tid >> 3][tid & 7] = tots[tid] / (tots[GN * CC + (tid >> 3)] + 1e-5f);
  __syncthreads();

  // block bx==0 persists centers+counts for the finalize; release each store
  if (blockIdx.x == 0 && tid < NVAL) {
    ws[WS_CEN + n * CEN_STRIDE + tid] =
        (tid < GN * CC) ? center[tid >> 3][tid & 7] : tots[tid];
    __threadfence();
  }

  // ---- variance pass ----
  const float* pn = preds + (size_t)n * CC * P_TOTAL;
  const int* tn = targets + (size_t)n * P_TOTAL;
  const int p4 = (blockIdx.x * 256 + tid) * 4;

  float accv = 0.0f;
  {
    int4 t4 = *reinterpret_cast<const int4*>(tn + p4);
    int t[4] = {t4.x, t4.y, t4.z, t4.w};
    float4 v4[CC];
#pragma unroll
    for (int c = 0; c < CC; ++c)
      v4[c] = *reinterpret_cast<const float4*>(pn + (size_t)c * P_TOTAL + p4);
    float v[CC][4];
#pragma unroll
    for (int c = 0; c < CC; ++c) {
      v[c][0] = v4[c].x; v[c][1] = v4[c].y; v[c][2] = v4[c].z; v[c][3] = v4[c].w;
    }
#pragma unroll
    for (int s = 0; s < 4; ++s) {
      int ts = t[s];
      if (ts > 0) {
        int g = ts - 1;
        float ss = 0.0f;
#pragma unroll
        for (int c = 0; c < CC; ++c) {
          float d = v[c][s] - center[g][c];
          ss = fmaf(d, d, ss);
        }
        float dn = sqrtf(ss);
        float cl = fmaxf(dn - 0.2f, 0.0f);
        accv = fmaf(cl, cl, accv);
      }
    }
  }

  WAVE_RED(accv);
  __shared__ float red[4];
  __shared__ int isLast;
  if (lane == 0) red[wv] = accv;
  __syncthreads();
  if (tid == 0) {
    ws[WS_VP + u] = red[0] + red[1] + red[2] + red[3];
    __threadfence();                               // release VP store
    int old = atomicAdd((int*)ws + WS_CNT, 1);
    isLast = (old == NUNIT - 1) ? 1 : 0;
  }
  __syncthreads();
  if (!isLast) return;

  // ---- last-arriving block: finalize ----
  __threadfence();                                 // acquire all VP/CEN stores

  __shared__ float vsum[NBATCH];
  __shared__ float res[NBATCH][3];
  {
    // wave w sums batch w's 175 var partials (3 independent loads/lane)
    float s = 0.0f;
    for (int j = lane; j < NBX; j += 64) s += ws[WS_VP + wv * NBX + j];
    WAVE_RED(s);
    if (lane == 0) vsum[wv] = s;
  }
  __syncthreads();

  if (tid < NBATCH) {
    const int nn = tid;
    const float* cb = ws + WS_CEN + nn * CEN_STRIDE;
    float cen[GN][CC];
    float has[GN];
    float ng = 0.0f;
#pragma unroll
    for (int g = 0; g < GN; ++g) {
      has[g] = (cb[GN * CC + g] > 0.0f) ? 1.0f : 0.0f;
      ng += has[g];
#pragma unroll
      for (int c = 0; c < CC; ++c) cen[g][c] = cb[g * CC + c];
    }
    float lv = vsum[nn] / ng;
    float ld = 0.0f;
#pragma unroll
    for (int i = 0; i < GN; ++i) {
#pragma unroll
      for (int j = 0; j < GN; ++j) {
        float ss = 0.0f;
#pragma unroll
        for (int c = 0; c < CC; ++c) {
          float d = cen[j][c] - cen[i][c];
          ss = fmaf(d, d, ss);
        }
        float dn = (ss > 0.0f) ? sqrtf(ss) : 0.0f;
        float cl = fmaxf(1.2f - dn, 0.0f);
        ld += cl * cl * has[i];
      }
    }
    ld /= fmaxf(ng * (ng - 1.0f), 1.0f);
    float lr = 0.0f;
#pragma unroll
    for (int g = 0; g < GN; ++g) {
      float cs = 0.0f;
#pragma unroll
      for (int c = 0; c < CC; ++c) cs += cen[g][c];
      lr += cs * cs * has[g];
    }
    res[nn][0] = ld;
    res[nn][1] = lv;
    res[nn][2] = lr;
  }
  __syncthreads();
  if (tid == 0) {
    float d = 0.0f, v = 0.0f, r = 0.0f;
#pragma unroll
    for (int nn = 0; nn < NBATCH; ++nn) {
      d += res[nn][0]; v += res[nn][1]; r += res[nn][2];
    }
    out[0] = d * 0.25f;
    out[1] = v * 0.25f * 0.01f;
    out[2] = r * 0.001f;
  }
}

extern "C" void kernel_launch(void* const* d_in, const int* in_sizes, int n_in,
                              void* d_out, int out_size, void* d_ws, size_t ws_size,
                              hipStream_t stream) {
  const float* preds = (const float*)d_in[0];
  const int* targets = (const int*)d_in[1];
  float* out = (float*)d_out;
  float* ws = (float*)d_ws;

  dim3 grid(NBX, NBATCH);   // (175, 4)
  k_accum<<<grid, 256, 0, stream>>>(preds, targets, ws);
  k_var<<<grid, 256, 0, stream>>>(preds, targets, ws, out);
}

// Round 11
// 82.431 us; speedup vs baseline: 1.1974x; 1.1974x over previous
//
#include <hip/hip_runtime.h>

// LaneNet discriminative loss, MI355X — 3-dispatch pipeline, ILP-safe reductions.
// preds: (4, 8, 280, 640) f32 ; targets: (4, 280, 640) i32 ; group_num = 5.
// out: [loss_dist, loss_var*0.01, loss_reg] f32.
//
// ws floats: PART [0, 700*45) ; VP [31500, 32200) ; CEN [32200, +4*48)
// All cross-block handoffs are plain stores + kernel boundary (coherent).
// R10 lesson: last-block atomic fusion costs ~16 µs (700-way same-line
// atomic across 8 XCDs); plain dispatch boundaries are cheaper. Keep 3.

#define P_TOTAL (280 * 640)   // 179200 = 175 * 256 * 4
#define NBATCH 4
#define GN 5
#define CC 8
#define NVAL (GN * CC + GN)   // 45
#define LPAD 47               // odd stride => conflict-free LDS transpose
#define NBX 175
#define NUNIT (NBX * NBATCH)  // 700
#define WS_VP (NUNIT * NVAL)  // 31500
#define WS_CEN (WS_VP + NUNIT)
#define CEN_STRIDE 48

#define WAVE_RED(x)                          \
  do {                                       \
    x += __shfl_xor(x, 32, 64);              \
    x += __shfl_xor(x, 16, 64);              \
    x += __shfl_xor(x, 8, 64);               \
    x += __shfl_xor(x, 4, 64);               \
    x += __shfl_xor(x, 2, 64);               \
    x += __shfl_xor(x, 1, 64);               \
  } while (0)

__global__ __launch_bounds__(256) void k_accum(const float* __restrict__ preds,
                                               const int* __restrict__ targets,
                                               float* __restrict__ ws) {
  const int n = blockIdx.y;
  const int u = n * NBX + blockIdx.x;
  const int tid = threadIdx.x;
  const int p4 = (blockIdx.x * 256 + tid) * 4;   // exact: 175*256*4 = P_TOTAL

  const float* pn = preds + (size_t)n * CC * P_TOTAL;
  const int* tn = targets + (size_t)n * P_TOTAL;

  float acc[GN][CC];
  float cnt[GN];
#pragma unroll
  for (int g = 0; g < GN; ++g) {
    cnt[g] = 0.0f;
#pragma unroll
    for (int c = 0; c < CC; ++c) acc[g][c] = 0.0f;
  }

  {
    int4 t4 = *reinterpret_cast<const int4*>(tn + p4);
    int t[4] = {t4.x, t4.y, t4.z, t4.w};
    float4 v4[CC];
#pragma unroll
    for (int c = 0; c < CC; ++c)
      v4[c] = *reinterpret_cast<const float4*>(pn + (size_t)c * P_TOTAL + p4);
    float v[CC][4];
#pragma unroll
    for (int c = 0; c < CC; ++c) {
      v[c][0] = v4[c].x; v[c][1] = v4[c].y; v[c][2] = v4[c].z; v[c][3] = v4[c].w;
    }
#pragma unroll
    for (int s = 0; s < 4; ++s) {
#pragma unroll
      for (int g = 0; g < GN; ++g) {
        float m = (t[s] == g + 1) ? 1.0f : 0.0f;
        cnt[g] += m;
#pragma unroll
        for (int c = 0; c < CC; ++c) acc[g][c] = fmaf(m, v[c][s], acc[g][c]);
      }
    }
  }

  // block reduction via LDS transpose
  __shared__ float buf[256][LPAD];
  __shared__ float part4[NVAL][4];
#pragma unroll
  for (int g = 0; g < GN; ++g) {
#pragma unroll
    for (int c = 0; c < CC; ++c) buf[tid][g * CC + c] = acc[g][c];
    buf[tid][GN * CC + g] = cnt[g];
  }
  __syncthreads();

  if (tid < NVAL * 4) {
    const int k = tid >> 2;
    const int part = tid & 3;
    float s = 0.0f;
#pragma unroll
    for (int r = 0; r < 64; ++r) s += buf[(r << 2) + part][k];
    part4[k][part] = s;
  }
  __syncthreads();

  if (tid < NVAL)
    ws[u * NVAL + tid] =
        part4[tid][0] + part4[tid][1] + part4[tid][2] + part4[tid][3];
}

__global__ __launch_bounds__(256) void k_var(const float* __restrict__ preds,
                                             const int* __restrict__ targets,
                                             float* __restrict__ ws) {
  const int n = blockIdx.y;
  const int u = n * NBX + blockIdx.x;
  const int tid = threadIdx.x;

  // ---- per-block center recompute from partials (L2-hot, ILP-deep) ----
  // 225 threads: (k, part) ; part covers 35 rows each ; loads independent.
  __shared__ float sums[NVAL][6];   // [k][part], padded
  __shared__ float tots[NVAL];
  __shared__ float center[GN][CC];
  if (tid < NVAL * 5) {
    const int k = tid % NVAL;
    const int part = tid / NVAL;    // 0..4
    const float* base = ws + ((size_t)n * NBX + part * 35) * NVAL + k;
    float s = 0.0f;
#pragma unroll
    for (int i = 0; i < 35; ++i) s += base[i * NVAL];
    sums[k][part] = s;
  }
  __syncthreads();
  if (tid < NVAL)
    tots[tid] = sums[tid][0] + sums[tid][1] + sums[tid][2] + sums[tid][3] +
                sums[tid][4];
  __syncthreads();
  if (tid < GN * CC)
    center[tid >> 3][tid & 7] = tots[tid] / (tots[GN * CC + (tid >> 3)] + 1e-5f);
  __syncthreads();

  // block bx==0 persists centers+counts for k_final
  if (blockIdx.x == 0 && tid < NVAL) {
    ws[WS_CEN + n * CEN_STRIDE + tid] =
        (tid < GN * CC) ? center[tid >> 3][tid & 7] : tots[tid];
  }

  // ---- variance pass ----
  const float* pn = preds + (size_t)n * CC * P_TOTAL;
  const int* tn = targets + (size_t)n * P_TOTAL;
  const int p4 = (blockIdx.x * 256 + tid) * 4;

  float accv = 0.0f;
  {
    int4 t4 = *reinterpret_cast<const int4*>(tn + p4);
    int t[4] = {t4.x, t4.y, t4.z, t4.w};
    float4 v4[CC];
#pragma unroll
    for (int c = 0; c < CC; ++c)
      v4[c] = *reinterpret_cast<const float4*>(pn + (size_t)c * P_TOTAL + p4);
    float v[CC][4];
#pragma unroll
    for (int c = 0; c < CC; ++c) {
      v[c][0] = v4[c].x; v[c][1] = v4[c].y; v[c][2] = v4[c].z; v[c][3] = v4[c].w;
    }
#pragma unroll
    for (int s = 0; s < 4; ++s) {
      int ts = t[s];
      if (ts > 0) {
        int g = ts - 1;
        float ss = 0.0f;
#pragma unroll
        for (int c = 0; c < CC; ++c) {
          float d = v[c][s] - center[g][c];
          ss = fmaf(d, d, ss);
        }
        float dn = sqrtf(ss);
        float cl = fmaxf(dn - 0.2f, 0.0f);
        accv = fmaf(cl, cl, accv);
      }
    }
  }

  WAVE_RED(accv);
  __shared__ float red[4];
  const int lane = tid & 63;
  const int wv = tid >> 6;
  if (lane == 0) red[wv] = accv;
  __syncthreads();
  if (tid == 0)
    ws[WS_VP + u] = red[0] + red[1] + red[2] + red[3];
}

__global__ __launch_bounds__(256) void k_final(const float* __restrict__ ws,
                                               float* __restrict__ out) {
  const int tid = threadIdx.x;
  const int lane = tid & 63;
  const int wv = tid >> 6;

  __shared__ float vsum[NBATCH];
  __shared__ float res[NBATCH][3];
  {
    // wave w sums batch w's 175 var partials (3 independent loads/lane)
    float s = 0.0f;
    for (int j = lane; j < NBX; j += 64) s += ws[WS_VP + wv * NBX + j];
    WAVE_RED(s);
    if (lane == 0) vsum[wv] = s;
  }
  __syncthreads();

  if (tid < NBATCH) {
    const int n = tid;
    const float* cb = ws + WS_CEN + n * CEN_STRIDE;
    float cen[GN][CC];
    float has[GN];
    float ng = 0.0f;
#pragma unroll
    for (int g = 0; g < GN; ++g) {
      has[g] = (cb[GN * CC + g] > 0.0f) ? 1.0f : 0.0f;
      ng += has[g];
#pragma unroll
      for (int c = 0; c < CC; ++c) cen[g][c] = cb[g * CC + c];
    }
    float lv = vsum[n] / ng;
    float ld = 0.0f;
#pragma unroll
    for (int i = 0; i < GN; ++i) {
#pragma unroll
      for (int j = 0; j < GN; ++j) {
        float ss = 0.0f;
#pragma unroll
        for (int c = 0; c < CC; ++c) {
          float d = cen[j][c] - cen[i][c];
          ss = fmaf(d, d, ss);
        }
        float dn = (ss > 0.0f) ? sqrtf(ss) : 0.0f;
        float cl = fmaxf(1.2f - dn, 0.0f);
        ld += cl * cl * has[i];
      }
    }
    ld /= fmaxf(ng * (ng - 1.0f), 1.0f);
    float lr = 0.0f;
#pragma unroll
    for (int g = 0; g < GN; ++g) {
      float cs = 0.0f;
#pragma unroll
      for (int c = 0; c < CC; ++c) cs += cen[g][c];
      lr += cs * cs * has[g];
    }
    res[n][0] = ld;
    res[n][1] = lv;
    res[n][2] = lr;
  }
  __syncthreads();
  if (tid == 0) {
    float d = 0.0f, v = 0.0f, r = 0.0f;
#pragma unroll
    for (int n = 0; n < NBATCH; ++n) {
      d += res[n][0]; v += res[n][1]; r += res[n][2];
    }
    out[0] = d * 0.25f;
    out[1] = v * 0.25f * 0.01f;
    out[2] = r * 0.001f;
  }
}

extern "C" void kernel_launch(void* const* d_in, const int* in_sizes, int n_in,
                              void* d_out, int out_size, void* d_ws, size_t ws_size,
                              hipStream_t stream) {
  const float* preds = (const float*)d_in[0];
  const int* targets = (const int*)d_in[1];
  float* out = (float*)d_out;
  float* ws = (float*)d_ws;

  dim3 grid(NBX, NBATCH);   // (175, 4)
  k_accum<<<grid, 256, 0, stream>>>(preds, targets, ws);
  k_var<<<grid, 256, 0, stream>>>(preds, targets, ws);
  k_final<<<1, 256, 0, stream>>>(ws, out);
}